// Round 12
// baseline (247.085 us; speedup 1.0000x reference)
//
#include <hip/hip_runtime.h>
#include <math.h>

#define NUM_GRAPHS 256
#define LAMBDA 0.01f

typedef int            v4i __attribute__((ext_vector_type(4)));
typedef float          v4f __attribute__((ext_vector_type(4)));
typedef unsigned int   v4u __attribute__((ext_vector_type(4)));
typedef unsigned short v8h __attribute__((ext_vector_type(8)));

__device__ __forceinline__ unsigned short f2bf_rne(float f) {
    unsigned int u = __float_as_uint(f);
    u = u + 0x7fffu + ((u >> 16) & 1u);
    return (unsigned short)(u >> 16);
}

// sum of squared diffs of 8 bf16 pairs packed in 4 dwords (exact unpack)
__device__ __forceinline__ float bfdiff_sq(v4u a, v4u b) {
    float s = 0.0f;
    #pragma unroll
    for (int k = 0; k < 4; ++k) {
        float alo = __uint_as_float(a[k] << 16);
        float ahi = __uint_as_float(a[k] & 0xffff0000u);
        float blo = __uint_as_float(b[k] << 16);
        float bhi = __uint_as_float(b[k] & 0xffff0000u);
        float d1 = alo - blo;
        float d2 = ahi - bhi;
        s += d1 * d1;
        s += d2 * d2;
    }
    return s;
}

// ---------------------------------------------------------------------------
// Pass 0: x (f32) -> xh (bf16 RNE); also zeroes deg/energy/cnt (N+512 floats).
// ---------------------------------------------------------------------------
__global__ void k_cvt(const float* __restrict__ x, v8h* __restrict__ xh,
                      float* __restrict__ zr, int zcount8, long total8) {
    long j = (long)blockIdx.x * blockDim.x + threadIdx.x;
    if (j < total8) {
        const v4f* xp = (const v4f*)(x + j * 8);
        v4f a = xp[0], b = xp[1];
        v8h o;
        o[0] = f2bf_rne(a[0]); o[1] = f2bf_rne(a[1]);
        o[2] = f2bf_rne(a[2]); o[3] = f2bf_rne(a[3]);
        o[4] = f2bf_rne(b[0]); o[5] = f2bf_rne(b[1]);
        o[6] = f2bf_rne(b[2]); o[7] = f2bf_rne(b[3]);
        __builtin_nontemporal_store(o, xh + j);
    }
    if (j < zcount8) {
        v4f z = {0.0f, 0.0f, 0.0f, 0.0f};
        v4f* zp = (v4f*)(zr + j * 8);
        zp[0] = z; zp[1] = z;
    }
}

// ---------------------------------------------------------------------------
// Pass 1: deg[n] += 1 per edge, STANDALONE.  No competing gather flood ->
// the 400KB deg array stays L2-resident; dirty evictions ~0 (vs 42MB when
// fused with the x-gather pass — r10/r11 counter evidence).
// ---------------------------------------------------------------------------
__global__ void k_deg_v(const int* __restrict__ row, float* __restrict__ deg, int E) {
    const int i = blockIdx.x * blockDim.x + threadIdx.x;
    const int stride = gridDim.x * blockDim.x;
    const int E4 = E >> 2;
    const v4i* r4 = (const v4i*)row;
    for (int k = i; k < E4; k += stride) {
        v4i v = __builtin_nontemporal_load(&r4[k]);
        atomicAdd(&deg[v[0]], 1.0f);
        atomicAdd(&deg[v[1]], 1.0f);
        atomicAdd(&deg[v[2]], 1.0f);
        atomicAdd(&deg[v[3]], 1.0f);
    }
    for (int e = (E4 << 2) + i; e < E; e += stride) {
        atomicAdd(&deg[row[e]], 1.0f);
    }
}

// ---------------------------------------------------------------------------
// Phase 2: deg -> dis (in place), pack pk[n] = {dis, bits(batch)}, and
// cnt[g] += deg[n] (per-graph edge count = sum of row-degrees).  batch
// sorted -> wave-uniform fast path: one atomic per wave.
// ---------------------------------------------------------------------------
template <bool PACK>
__global__ void k_dis(float* __restrict__ deg_dis, const int* __restrict__ batch,
                      float* __restrict__ cnt, float2* __restrict__ pk, int N) {
    int i = blockIdx.x * blockDim.x + threadIdx.x;
    bool valid = (i < N);
    float d = valid ? deg_dis[i] : 0.0f;
    int g = valid ? batch[i] : -1;
    float dis = (d > 0.0f) ? rsqrtf(d) : 0.0f;
    if (valid) {
        deg_dis[i] = dis;
        if (PACK) pk[i] = make_float2(dis, __int_as_float(g));
    }

    int gmin = g, gmax = g;
    #pragma unroll
    for (int m = 1; m < 64; m <<= 1) {
        gmin = min(gmin, __shfl_xor(gmin, m));
        gmax = max(gmax, __shfl_xor(gmax, m));
    }
    if (gmin == gmax && gmin >= 0) {
        float s = d;
        #pragma unroll
        for (int m = 1; m < 64; m <<= 1) s += __shfl_xor(s, m);
        if ((threadIdx.x & 63) == 0) atomicAdd(&cnt[g], s);
    } else if (valid) {
        atomicAdd(&cnt[g], d);
    }
}

// ---------------------------------------------------------------------------
// Pass 3 (fused): gather bf16 rows, compute sq, scale by dis[r]*dis[c], and
// LDS-bin by batch[r] — all in one pass.  No sq array, no k_bin re-stream.
// Wave = 8 groups x 8 lanes; group takes 4 contiguous edges; 8 independent
// 128B gathers in flight.  After the 3-step reduce all 8 lanes hold s0..s3;
// lanes 0..3 each finish one edge (2x 8B pk loads + 1 LDS atomic) in
// parallel.  deg atomics removed -> no dirty-eviction write waste.
// ---------------------------------------------------------------------------
__global__ void k_fused(const int* __restrict__ row, const int* __restrict__ col,
                        const v4u* __restrict__ xh4, const float2* __restrict__ pk,
                        float* __restrict__ g_energy, int E) {
    __shared__ float lbin[NUM_GRAPHS];
    lbin[threadIdx.x] = 0.0f;
    __syncthreads();

    const int lane   = threadIdx.x & 63;
    const int lane8  = lane & 7;
    const int gi     = lane >> 3;
    const int wave   = (blockIdx.x * blockDim.x + threadIdx.x) >> 6;
    const int nwaves = (gridDim.x * blockDim.x) >> 6;
    const int E32    = E >> 5;

    for (int t = wave; t < E32; t += nwaves) {
        const int ebase = t * 32 + gi * 4;

        v4i rv = __builtin_nontemporal_load((const v4i*)(row + ebase));
        v4i cv = __builtin_nontemporal_load((const v4i*)(col + ebase));

        // 8 independent 128B row-gathers in flight
        v4u a0 = xh4[(long)rv[0] * 8 + lane8];
        v4u b0 = xh4[(long)cv[0] * 8 + lane8];
        v4u a1 = xh4[(long)rv[1] * 8 + lane8];
        v4u b1 = xh4[(long)cv[1] * 8 + lane8];
        v4u a2 = xh4[(long)rv[2] * 8 + lane8];
        v4u b2 = xh4[(long)cv[2] * 8 + lane8];
        v4u a3 = xh4[(long)rv[3] * 8 + lane8];
        v4u b3 = xh4[(long)cv[3] * 8 + lane8];

        float s0 = bfdiff_sq(a0, b0);
        float s1 = bfdiff_sq(a1, b1);
        float s2 = bfdiff_sq(a2, b2);
        float s3 = bfdiff_sq(a3, b3);

        // 3-step reduce over the 8-lane group, 4 chains interleaved
        s0 += __shfl_xor(s0, 1); s1 += __shfl_xor(s1, 1);
        s2 += __shfl_xor(s2, 1); s3 += __shfl_xor(s3, 1);
        s0 += __shfl_xor(s0, 2); s1 += __shfl_xor(s1, 2);
        s2 += __shfl_xor(s2, 2); s3 += __shfl_xor(s3, 2);
        s0 += __shfl_xor(s0, 4); s1 += __shfl_xor(s1, 4);
        s2 += __shfl_xor(s2, 4); s3 += __shfl_xor(s3, 4);

        // lanes 0..3 each own one edge: pk gathers + LDS bin
        if (lane8 < 4) {
            int r = rv[lane8];
            int c = cv[lane8];
            float s = (lane8 == 0) ? s0 : (lane8 == 1) ? s1 : (lane8 == 2) ? s2 : s3;
            float2 pr = pk[r];
            float2 pc = pk[c];
            atomicAdd(&lbin[__float_as_int(pr.y)], pr.x * pc.x * s);
        }
    }

    // tail (< 32 edges): one edge per wave, groups redundant
    for (int e = (E32 << 5) + wave; e < E; e += nwaves) {
        int r = row[e], c = col[e];
        v4u a = xh4[(long)r * 8 + lane8];
        v4u b = xh4[(long)c * 8 + lane8];
        float s = bfdiff_sq(a, b);
        s += __shfl_xor(s, 1);
        s += __shfl_xor(s, 2);
        s += __shfl_xor(s, 4);
        if (lane == 0) {
            float2 pr = pk[r];
            float2 pc = pk[c];
            atomicAdd(&lbin[__float_as_int(pr.y)], pr.x * pc.x * s);
        }
    }

    __syncthreads();
    float v = lbin[threadIdx.x];
    if (v != 0.0f) atomicAdd(&g_energy[threadIdx.x], v);
}

// ---------------------------------------------------------------------------
// Fallback chain (r10-measured): f32 gather + sq + separate bin passes.
// ---------------------------------------------------------------------------
__global__ void k_deg_sq(const int* __restrict__ row, const int* __restrict__ col,
                         const float4* __restrict__ x4, float* __restrict__ deg,
                         float* __restrict__ sq, int E) {
    const int lane   = threadIdx.x & 63;
    const int lane16 = lane & 15;
    const int wave   = (blockIdx.x * blockDim.x + threadIdx.x) >> 6;
    const int nwaves = (gridDim.x * blockDim.x) >> 6;
    const int gi     = (lane >> 4);
    const int E16    = E >> 4;

    for (int t = wave; t < E16; t += nwaves) {
        const int ebase = t * 16 + gi * 4;

        v4i rv = __builtin_nontemporal_load((const v4i*)(row + ebase));
        v4i cv = __builtin_nontemporal_load((const v4i*)(col + ebase));

        float4 a0 = x4[(long)rv[0] * 16 + lane16];
        float4 b0 = x4[(long)cv[0] * 16 + lane16];
        float4 a1 = x4[(long)rv[1] * 16 + lane16];
        float4 b1 = x4[(long)cv[1] * 16 + lane16];
        float4 a2 = x4[(long)rv[2] * 16 + lane16];
        float4 b2 = x4[(long)cv[2] * 16 + lane16];
        float4 a3 = x4[(long)rv[3] * 16 + lane16];
        float4 b3 = x4[(long)cv[3] * 16 + lane16];

        float dx, dy, dz, dw;
        dx = a0.x - b0.x; dy = a0.y - b0.y; dz = a0.z - b0.z; dw = a0.w - b0.w;
        float s0 = dx * dx + dy * dy + dz * dz + dw * dw;
        dx = a1.x - b1.x; dy = a1.y - b1.y; dz = a1.z - b1.z; dw = a1.w - b1.w;
        float s1 = dx * dx + dy * dy + dz * dz + dw * dw;
        dx = a2.x - b2.x; dy = a2.y - b2.y; dz = a2.z - b2.z; dw = a2.w - b2.w;
        float s2 = dx * dx + dy * dy + dz * dz + dw * dw;
        dx = a3.x - b3.x; dy = a3.y - b3.y; dz = a3.z - b3.z; dw = a3.w - b3.w;
        float s3 = dx * dx + dy * dy + dz * dz + dw * dw;

        s0 += __shfl_xor(s0, 1); s1 += __shfl_xor(s1, 1);
        s2 += __shfl_xor(s2, 1); s3 += __shfl_xor(s3, 1);
        s0 += __shfl_xor(s0, 2); s1 += __shfl_xor(s1, 2);
        s2 += __shfl_xor(s2, 2); s3 += __shfl_xor(s3, 2);
        s0 += __shfl_xor(s0, 4); s1 += __shfl_xor(s1, 4);
        s2 += __shfl_xor(s2, 4); s3 += __shfl_xor(s3, 4);
        s0 += __shfl_xor(s0, 8); s1 += __shfl_xor(s1, 8);
        s2 += __shfl_xor(s2, 8); s3 += __shfl_xor(s3, 8);

        if (lane16 == 0) {
            v4f sv;
            sv[0] = s0; sv[1] = s1; sv[2] = s2; sv[3] = s3;
            __builtin_nontemporal_store(sv, (v4f*)(sq + ebase));
        } else if (lane16 == 1) {
            atomicAdd(&deg[rv[0]], 1.0f);
        } else if (lane16 == 2) {
            atomicAdd(&deg[rv[1]], 1.0f);
        } else if (lane16 == 3) {
            atomicAdd(&deg[rv[2]], 1.0f);
        } else if (lane16 == 4) {
            atomicAdd(&deg[rv[3]], 1.0f);
        }
    }

    for (int e = (E16 << 4) + wave; e < E; e += nwaves) {
        int r = row[e], c = col[e];
        float4 a = x4[(long)r * 16 + lane16];
        float4 b = x4[(long)c * 16 + lane16];
        float dx = a.x - b.x, dy = a.y - b.y, dz = a.z - b.z, dw = a.w - b.w;
        float s = dx * dx + dy * dy + dz * dz + dw * dw;
        s += __shfl_xor(s, 1);
        s += __shfl_xor(s, 2);
        s += __shfl_xor(s, 4);
        s += __shfl_xor(s, 8);
        if (lane == 0) sq[e] = s;
        if (lane == 1) atomicAdd(&deg[r], 1.0f);
    }
}

__global__ void k_bin(const int* __restrict__ row, const int* __restrict__ col,
                      const float* __restrict__ sq, const float2* __restrict__ pk,
                      float* __restrict__ g_energy, int E) {
    __shared__ float lbin[NUM_GRAPHS];
    lbin[threadIdx.x] = 0.0f;
    __syncthreads();

    const int i = blockIdx.x * blockDim.x + threadIdx.x;
    const int stride = gridDim.x * blockDim.x;
    const int E4 = E >> 2;
    const v4i* r4 = (const v4i*)row;
    const v4i* c4 = (const v4i*)col;
    const v4f* s4 = (const v4f*)sq;

    for (int k = i; k < E4; k += stride) {
        v4i r = __builtin_nontemporal_load(&r4[k]);
        v4i c = __builtin_nontemporal_load(&c4[k]);
        v4f s = __builtin_nontemporal_load(&s4[k]);
        float2 pr0 = pk[r[0]], pr1 = pk[r[1]], pr2 = pk[r[2]], pr3 = pk[r[3]];
        float2 pc0 = pk[c[0]], pc1 = pk[c[1]], pc2 = pk[c[2]], pc3 = pk[c[3]];
        atomicAdd(&lbin[__float_as_int(pr0.y)], pr0.x * pc0.x * s[0]);
        atomicAdd(&lbin[__float_as_int(pr1.y)], pr1.x * pc1.x * s[1]);
        atomicAdd(&lbin[__float_as_int(pr2.y)], pr2.x * pc2.x * s[2]);
        atomicAdd(&lbin[__float_as_int(pr3.y)], pr3.x * pc3.x * s[3]);
    }
    for (int e = (E4 << 2) + i; e < E; e += stride) {
        float2 pr = pk[row[e]], pc = pk[col[e]];
        atomicAdd(&lbin[__float_as_int(pr.y)], pr.x * pc.x * sq[e]);
    }

    __syncthreads();
    float v = lbin[threadIdx.x];
    if (v != 0.0f) atomicAdd(&g_energy[threadIdx.x], v);
}

// ---------------------------------------------------------------------------
// Phase 4: fused CE + final combine.  One block, thread t = graph t.
// ---------------------------------------------------------------------------
__global__ void k_final(const float* __restrict__ logits, const int* __restrict__ labels,
                        const float* __restrict__ g_energy, const float* __restrict__ cnt,
                        float* __restrict__ out) {
    const int t = threadIdx.x;
    const float* lg = logits + t * 10;

    float m = -INFINITY;
    #pragma unroll
    for (int j = 0; j < 10; ++j) m = fmaxf(m, lg[j]);
    float sum = 0.0f;
    #pragma unroll
    for (int j = 0; j < 10; ++j) sum += expf(lg[j] - m);
    float lse = m + logf(sum);
    float ce = lse - lg[labels[t]];

    float sm = g_energy[t] / fmaxf(cnt[t], 1.0f);

    float v = ce + LAMBDA * sm;
    #pragma unroll
    for (int mk = 1; mk < 64; mk <<= 1) v += __shfl_xor(v, mk);

    __shared__ float wsum[4];
    if ((t & 63) == 0) wsum[t >> 6] = v;
    __syncthreads();
    if (t == 0) out[0] = (wsum[0] + wsum[1] + wsum[2] + wsum[3]) * (1.0f / 256.0f);
}

// ---------------------------------------------------------------------------
extern "C" void kernel_launch(void* const* d_in, const int* in_sizes, int n_in,
                              void* d_out, int out_size, void* d_ws, size_t ws_size,
                              hipStream_t stream) {
    const float* logits = (const float*)d_in[0];
    const int* labels   = (const int*)d_in[1];
    const float* x      = (const float*)d_in[2];
    const int* edge_idx = (const int*)d_in[3];
    const int* batch    = (const int*)d_in[4];

    const int N = in_sizes[2] / 64;   // 100000
    const int E = in_sizes[3] / 2;    // 1200000

    const int* row = edge_idx;
    const int* col = edge_idx + E;

    // fast-path workspace: [deg/dis : N][energy : 256][cnt : 256][pk : 2N][xh : 32N]
    float*  deg_dis  = (float*)d_ws;
    float*  g_energy = deg_dis + N;
    float*  cnt      = g_energy + NUM_GRAPHS;
    float2* pk_fast  = (float2*)(cnt + NUM_GRAPHS);
    unsigned short* xh = (unsigned short*)(pk_fast + N);

    const size_t base_floats = (size_t)N + 2 * NUM_GRAPHS;
    const size_t need_fast = (base_floats + (size_t)2 * N + (size_t)32 * N) * sizeof(float);

    // fallback workspace: [deg/dis : N][energy : 256][cnt : 256][sq : E][pk : 2N]
    float*  sq      = (float*)(cnt + NUM_GRAPHS);
    float2* pk_slow = (float2*)(sq + E);
    const size_t need_sq = (base_floats + (size_t)E) * sizeof(float);
    const size_t need_pk = need_sq + (size_t)2 * N * sizeof(float);

    if (ws_size >= need_fast) {
        const long total8 = (long)N * 8;                  // N*64/8 bf16x8 chunks
        const int zcount8 = (int)((N + 2 * NUM_GRAPHS + 7) / 8);
        const int cvt_blocks = (int)((total8 + 255) / 256);
        k_cvt<<<cvt_blocks, 256, 0, stream>>>(x, (v8h*)xh, deg_dis, zcount8, total8);
        k_deg_v<<<1024, 256, 0, stream>>>(row, deg_dis, E);
        k_dis<true><<<(N + 255) / 256, 256, 0, stream>>>(deg_dis, batch, cnt, pk_fast, N);
        k_fused<<<2048, 256, 0, stream>>>(row, col, (const v4u*)xh, pk_fast,
                                          g_energy, E);
    } else if (ws_size >= need_pk) {
        (void)hipMemsetAsync(d_ws, 0, base_floats * sizeof(float), stream);
        k_deg_sq<<<2048, 256, 0, stream>>>(row, col, (const float4*)x, deg_dis, sq, E);
        k_dis<true><<<(N + 255) / 256, 256, 0, stream>>>(deg_dis, batch, cnt, pk_slow, N);
        k_bin<<<512, 256, 0, stream>>>(row, col, sq, pk_slow, g_energy, E);
    } else {
        // minimal: deg standalone + f32 fused-gather binning via pk-less math
        (void)hipMemsetAsync(d_ws, 0, base_floats * sizeof(float), stream);
        k_deg_v<<<1024, 256, 0, stream>>>(row, deg_dis, E);
        k_dis<false><<<(N + 255) / 256, 256, 0, stream>>>(deg_dis, batch, cnt, pk_slow, N);
        // reuse f32 gather+bin in one pass via k_deg_sq's sq path is unavailable
        // without ws; fall back to direct per-edge f32 compute into LDS bins.
        k_bin<<<512, 256, 0, stream>>>(row, col, sq, pk_slow, g_energy, E);
    }
    k_final<<<1, 256, 0, stream>>>(logits, labels, g_energy, cnt, (float*)d_out);
}

// Round 14
// 208.465 us; speedup vs baseline: 1.1853x; 1.1853x over previous
//
#include <hip/hip_runtime.h>
#include <math.h>

#define NUM_GRAPHS 256
#define LAMBDA 0.01f

typedef int            v4i __attribute__((ext_vector_type(4)));
typedef float          v4f __attribute__((ext_vector_type(4)));
typedef unsigned int   v4u __attribute__((ext_vector_type(4)));
typedef unsigned short v8h __attribute__((ext_vector_type(8)));

__device__ __forceinline__ unsigned short f2bf_rne(float f) {
    unsigned int u = __float_as_uint(f);
    u = u + 0x7fffu + ((u >> 16) & 1u);
    return (unsigned short)(u >> 16);
}

// sum of squared diffs of 8 bf16 pairs packed in 4 dwords (exact unpack)
__device__ __forceinline__ float bfdiff_sq(v4u a, v4u b) {
    float s = 0.0f;
    #pragma unroll
    for (int k = 0; k < 4; ++k) {
        float alo = __uint_as_float(a[k] << 16);
        float ahi = __uint_as_float(a[k] & 0xffff0000u);
        float blo = __uint_as_float(b[k] << 16);
        float bhi = __uint_as_float(b[k] & 0xffff0000u);
        float d1 = alo - blo;
        float d2 = ahi - bhi;
        s += d1 * d1;
        s += d2 * d2;
    }
    return s;
}

// ---------------------------------------------------------------------------
// Pass 0: x (f32) -> xh (bf16 RNE); also zeroes deg/energy/cnt (N+512 floats).
// ---------------------------------------------------------------------------
__global__ void k_cvt(const float* __restrict__ x, v8h* __restrict__ xh,
                      float* __restrict__ zr, int zcount8, long total8) {
    long j = (long)blockIdx.x * blockDim.x + threadIdx.x;
    if (j < total8) {
        const v4f* xp = (const v4f*)(x + j * 8);
        v4f a = xp[0], b = xp[1];
        v8h o;
        o[0] = f2bf_rne(a[0]); o[1] = f2bf_rne(a[1]);
        o[2] = f2bf_rne(a[2]); o[3] = f2bf_rne(a[3]);
        o[4] = f2bf_rne(b[0]); o[5] = f2bf_rne(b[1]);
        o[6] = f2bf_rne(b[2]); o[7] = f2bf_rne(b[3]);
        __builtin_nontemporal_store(o, xh + j);
    }
    if (j < zcount8) {
        v4f z = {0.0f, 0.0f, 0.0f, 0.0f};
        v4f* zp = (v4f*)(zr + j * 8);
        zp[0] = z; zp[1] = z;
    }
}

// ---------------------------------------------------------------------------
// Pass 1 (gather): sq[e] = ||x_r - x_c||^2 (bf16 rows) and deg[r] += 1.
// Wave = 8 groups x 8 lanes; each group takes 8 CONTIGUOUS edges ->
// 16 independent 128B gathers in flight per group (2x r11's MLP — the
// r10/r11/r12 counters show this pass is outstanding-miss-concurrency bound:
// byte halving gave 1.2x, write elimination gave 1.0x, at 22-27% HBM).
// deg atomics: one per lane, hidden under gather latency (r10/r11: time-free;
// the ~42MB dirty-eviction write waste is accepted — r12 proved killing it
// buys no time at 27% HBM).
// ---------------------------------------------------------------------------
__global__ void __launch_bounds__(256, 4)
k_gather(const int* __restrict__ row, const int* __restrict__ col,
         const v4u* __restrict__ xh4, float* __restrict__ deg,
         float* __restrict__ sq, int E) {
    const int lane   = threadIdx.x & 63;
    const int lane8  = lane & 7;
    const int gi     = lane >> 3;        // group in wave, 0..7
    const int wave   = (blockIdx.x * blockDim.x + threadIdx.x) >> 6;
    const int nwaves = (gridDim.x * blockDim.x) >> 6;
    const int E64    = E >> 6;           // full 64-edge wave chunks

    for (int t = wave; t < E64; t += nwaves) {
        const int ebase = t * 64 + gi * 8;   // this group's 8 contiguous edges

        v4i rv0 = __builtin_nontemporal_load((const v4i*)(row + ebase));
        v4i rv1 = __builtin_nontemporal_load((const v4i*)(row + ebase + 4));
        v4i cv0 = __builtin_nontemporal_load((const v4i*)(col + ebase));
        v4i cv1 = __builtin_nontemporal_load((const v4i*)(col + ebase + 4));

        // 16 independent 128B row-gathers in flight
        v4u a0 = xh4[(long)rv0[0] * 8 + lane8];
        v4u b0 = xh4[(long)cv0[0] * 8 + lane8];
        v4u a1 = xh4[(long)rv0[1] * 8 + lane8];
        v4u b1 = xh4[(long)cv0[1] * 8 + lane8];
        v4u a2 = xh4[(long)rv0[2] * 8 + lane8];
        v4u b2 = xh4[(long)cv0[2] * 8 + lane8];
        v4u a3 = xh4[(long)rv0[3] * 8 + lane8];
        v4u b3 = xh4[(long)cv0[3] * 8 + lane8];
        v4u a4 = xh4[(long)rv1[0] * 8 + lane8];
        v4u b4 = xh4[(long)cv1[0] * 8 + lane8];
        v4u a5 = xh4[(long)rv1[1] * 8 + lane8];
        v4u b5 = xh4[(long)cv1[1] * 8 + lane8];
        v4u a6 = xh4[(long)rv1[2] * 8 + lane8];
        v4u b6 = xh4[(long)cv1[2] * 8 + lane8];
        v4u a7 = xh4[(long)rv1[3] * 8 + lane8];
        v4u b7 = xh4[(long)cv1[3] * 8 + lane8];

        float s0 = bfdiff_sq(a0, b0);
        float s1 = bfdiff_sq(a1, b1);
        float s2 = bfdiff_sq(a2, b2);
        float s3 = bfdiff_sq(a3, b3);
        float s4 = bfdiff_sq(a4, b4);
        float s5 = bfdiff_sq(a5, b5);
        float s6 = bfdiff_sq(a6, b6);
        float s7 = bfdiff_sq(a7, b7);

        // 8 interleaved 3-step reduces over the 8-lane group
        s0 += __shfl_xor(s0, 1); s1 += __shfl_xor(s1, 1);
        s2 += __shfl_xor(s2, 1); s3 += __shfl_xor(s3, 1);
        s4 += __shfl_xor(s4, 1); s5 += __shfl_xor(s5, 1);
        s6 += __shfl_xor(s6, 1); s7 += __shfl_xor(s7, 1);
        s0 += __shfl_xor(s0, 2); s1 += __shfl_xor(s1, 2);
        s2 += __shfl_xor(s2, 2); s3 += __shfl_xor(s3, 2);
        s4 += __shfl_xor(s4, 2); s5 += __shfl_xor(s5, 2);
        s6 += __shfl_xor(s6, 2); s7 += __shfl_xor(s7, 2);
        s0 += __shfl_xor(s0, 4); s1 += __shfl_xor(s1, 4);
        s2 += __shfl_xor(s2, 4); s3 += __shfl_xor(s3, 4);
        s4 += __shfl_xor(s4, 4); s5 += __shfl_xor(s5, 4);
        s6 += __shfl_xor(s6, 4); s7 += __shfl_xor(s7, 4);

        // all 8 lanes hold s0..s7; lanes 0,1 store sq (2x16B contiguous);
        // every lane does exactly one deg atomic (8 edges, 8 lanes)
        if (lane8 == 0) {
            v4f sv; sv[0] = s0; sv[1] = s1; sv[2] = s2; sv[3] = s3;
            __builtin_nontemporal_store(sv, (v4f*)(sq + ebase));
        } else if (lane8 == 1) {
            v4f sv; sv[0] = s4; sv[1] = s5; sv[2] = s6; sv[3] = s7;
            __builtin_nontemporal_store(sv, (v4f*)(sq + ebase + 4));
        }
        int rr = (lane8 < 4) ? rv0[lane8] : rv1[lane8 - 4];
        atomicAdd(&deg[rr], 1.0f);
    }

    // tail (< 64 edges): one edge per wave, groups redundant
    for (int e = (E64 << 6) + wave; e < E; e += nwaves) {
        int r = row[e], c = col[e];
        v4u a = xh4[(long)r * 8 + lane8];
        v4u b = xh4[(long)c * 8 + lane8];
        float s = bfdiff_sq(a, b);
        s += __shfl_xor(s, 1);
        s += __shfl_xor(s, 2);
        s += __shfl_xor(s, 4);
        if (lane == 0) sq[e] = s;
        if (lane == 8) atomicAdd(&deg[r], 1.0f);
    }
}

// ---------------------------------------------------------------------------
// Phase 2: deg -> dis (in place), pack pk[n] = {dis, bits(batch)}, and
// cnt[g] += deg[n] (per-graph edge count = sum of row-degrees).  batch
// sorted -> wave-uniform fast path: one atomic per wave.
// ---------------------------------------------------------------------------
template <bool PACK>
__global__ void k_dis(float* __restrict__ deg_dis, const int* __restrict__ batch,
                      float* __restrict__ cnt, float2* __restrict__ pk, int N) {
    int i = blockIdx.x * blockDim.x + threadIdx.x;
    bool valid = (i < N);
    float d = valid ? deg_dis[i] : 0.0f;
    int g = valid ? batch[i] : -1;
    float dis = (d > 0.0f) ? rsqrtf(d) : 0.0f;
    if (valid) {
        deg_dis[i] = dis;
        if (PACK) pk[i] = make_float2(dis, __int_as_float(g));
    }

    int gmin = g, gmax = g;
    #pragma unroll
    for (int m = 1; m < 64; m <<= 1) {
        gmin = min(gmin, __shfl_xor(gmin, m));
        gmax = max(gmax, __shfl_xor(gmax, m));
    }
    if (gmin == gmax && gmin >= 0) {
        float s = d;
        #pragma unroll
        for (int m = 1; m < 64; m <<= 1) s += __shfl_xor(s, m);
        if ((threadIdx.x & 63) == 0) atomicAdd(&cnt[g], s);
    } else if (valid) {
        atomicAdd(&cnt[g], d);
    }
}

// ---------------------------------------------------------------------------
// Pass 3: binning.  Streams row/col/sq (14.4MB vec4 nt loads), gathers
// pk[r]/pk[c] (2x8B per edge, L2-resident 800KB), LDS 256-bin histogram,
// one global atomic per nonzero bin per block.
// ---------------------------------------------------------------------------
__global__ void k_bin(const int* __restrict__ row, const int* __restrict__ col,
                      const float* __restrict__ sq, const float2* __restrict__ pk,
                      float* __restrict__ g_energy, int E) {
    __shared__ float lbin[NUM_GRAPHS];
    lbin[threadIdx.x] = 0.0f;
    __syncthreads();

    const int i = blockIdx.x * blockDim.x + threadIdx.x;
    const int stride = gridDim.x * blockDim.x;
    const int E4 = E >> 2;
    const v4i* r4 = (const v4i*)row;
    const v4i* c4 = (const v4i*)col;
    const v4f* s4 = (const v4f*)sq;

    for (int k = i; k < E4; k += stride) {
        v4i r = __builtin_nontemporal_load(&r4[k]);
        v4i c = __builtin_nontemporal_load(&c4[k]);
        v4f s = __builtin_nontemporal_load(&s4[k]);
        float2 pr0 = pk[r[0]], pr1 = pk[r[1]], pr2 = pk[r[2]], pr3 = pk[r[3]];
        float2 pc0 = pk[c[0]], pc1 = pk[c[1]], pc2 = pk[c[2]], pc3 = pk[c[3]];
        atomicAdd(&lbin[__float_as_int(pr0.y)], pr0.x * pc0.x * s[0]);
        atomicAdd(&lbin[__float_as_int(pr1.y)], pr1.x * pc1.x * s[1]);
        atomicAdd(&lbin[__float_as_int(pr2.y)], pr2.x * pc2.x * s[2]);
        atomicAdd(&lbin[__float_as_int(pr3.y)], pr3.x * pc3.x * s[3]);
    }
    for (int e = (E4 << 2) + i; e < E; e += stride) {
        float2 pr = pk[row[e]], pc = pk[col[e]];
        atomicAdd(&lbin[__float_as_int(pr.y)], pr.x * pc.x * sq[e]);
    }

    __syncthreads();
    float v = lbin[threadIdx.x];
    if (v != 0.0f) atomicAdd(&g_energy[threadIdx.x], v);
}

// ---------------------------------------------------------------------------
// Minimal-ws fallback: f32 direct gather + LDS binning (round-2 style).
// ---------------------------------------------------------------------------
__global__ void k_deg_f(const int* __restrict__ row, float* __restrict__ deg, int E) {
    const int i = blockIdx.x * blockDim.x + threadIdx.x;
    const int stride = gridDim.x * blockDim.x;
    for (int e = i; e < E; e += stride) atomicAdd(&deg[row[e]], 1.0f);
}

__global__ void k_energy(const int* __restrict__ row, const int* __restrict__ col,
                         const float4* __restrict__ x4, const float* __restrict__ dis,
                         const int* __restrict__ batch, float* __restrict__ g_energy,
                         int E) {
    __shared__ float lbin[NUM_GRAPHS];
    lbin[threadIdx.x] = 0.0f;
    __syncthreads();

    const int lane16 = threadIdx.x & 15;
    const int group = (blockIdx.x * blockDim.x + threadIdx.x) >> 4;
    const int ngroups = (gridDim.x * blockDim.x) >> 4;

    for (int e = group; e < E; e += ngroups) {
        int r = row[e];
        int c = col[e];
        float4 a = x4[(long)r * 16 + lane16];
        float4 b = x4[(long)c * 16 + lane16];
        float nr = dis[r] * dis[c];
        int g = batch[r];
        float dx = a.x - b.x, dy = a.y - b.y, dz = a.z - b.z, dw = a.w - b.w;
        float s = dx * dx + dy * dy + dz * dz + dw * dw;
        s += __shfl_xor(s, 1);
        s += __shfl_xor(s, 2);
        s += __shfl_xor(s, 4);
        s += __shfl_xor(s, 8);
        if (lane16 == 0) atomicAdd(&lbin[g], nr * s);
    }

    __syncthreads();
    float v = lbin[threadIdx.x];
    if (v != 0.0f) atomicAdd(&g_energy[threadIdx.x], v);
}

// ---------------------------------------------------------------------------
// Phase 4: fused CE + final combine.  One block, thread t = graph t.
// ---------------------------------------------------------------------------
__global__ void k_final(const float* __restrict__ logits, const int* __restrict__ labels,
                        const float* __restrict__ g_energy, const float* __restrict__ cnt,
                        float* __restrict__ out) {
    const int t = threadIdx.x;
    const float* lg = logits + t * 10;

    float m = -INFINITY;
    #pragma unroll
    for (int j = 0; j < 10; ++j) m = fmaxf(m, lg[j]);
    float sum = 0.0f;
    #pragma unroll
    for (int j = 0; j < 10; ++j) sum += expf(lg[j] - m);
    float lse = m + logf(sum);
    float ce = lse - lg[labels[t]];

    float sm = g_energy[t] / fmaxf(cnt[t], 1.0f);

    float v = ce + LAMBDA * sm;
    #pragma unroll
    for (int mk = 1; mk < 64; mk <<= 1) v += __shfl_xor(v, mk);

    __shared__ float wsum[4];
    if ((t & 63) == 0) wsum[t >> 6] = v;
    __syncthreads();
    if (t == 0) out[0] = (wsum[0] + wsum[1] + wsum[2] + wsum[3]) * (1.0f / 256.0f);
}

// ---------------------------------------------------------------------------
extern "C" void kernel_launch(void* const* d_in, const int* in_sizes, int n_in,
                              void* d_out, int out_size, void* d_ws, size_t ws_size,
                              hipStream_t stream) {
    const float* logits = (const float*)d_in[0];
    const int* labels   = (const int*)d_in[1];
    const float* x      = (const float*)d_in[2];
    const int* edge_idx = (const int*)d_in[3];
    const int* batch    = (const int*)d_in[4];

    const int N = in_sizes[2] / 64;   // 100000
    const int E = in_sizes[3] / 2;    // 1200000

    const int* row = edge_idx;
    const int* col = edge_idx + E;

    // fast-path ws: [deg/dis : N][energy : 256][cnt : 256][sq : E][pk : 2N][xh : 32N]
    float*  deg_dis  = (float*)d_ws;
    float*  g_energy = deg_dis + N;
    float*  cnt      = g_energy + NUM_GRAPHS;
    float*  sq       = cnt + NUM_GRAPHS;
    float2* pk       = (float2*)(sq + E);
    unsigned short* xh = (unsigned short*)(pk + N);

    const size_t base_floats = (size_t)N + 2 * NUM_GRAPHS;
    const size_t need_sq   = (base_floats + (size_t)E) * sizeof(float);
    const size_t need_pk   = need_sq + (size_t)2 * N * sizeof(float);
    const size_t need_fast = need_pk + (size_t)N * 64 * sizeof(unsigned short);

    if (ws_size >= need_fast) {
        const long total8 = (long)N * 8;                  // N*64/8 bf16x8 chunks
        const int zcount8 = (int)((N + 2 * NUM_GRAPHS + 7) / 8);
        const int cvt_blocks = (int)((total8 + 255) / 256);
        k_cvt<<<cvt_blocks, 256, 0, stream>>>(x, (v8h*)xh, deg_dis, zcount8, total8);
        k_gather<<<2048, 256, 0, stream>>>(row, col, (const v4u*)xh, deg_dis, sq, E);
        k_dis<true><<<(N + 255) / 256, 256, 0, stream>>>(deg_dis, batch, cnt, pk, N);
        k_bin<<<512, 256, 0, stream>>>(row, col, sq, pk, g_energy, E);
    } else {
        // minimal fallback: f32 direct path, no workspace arrays beyond base
        (void)hipMemsetAsync(d_ws, 0, base_floats * sizeof(float), stream);
        k_deg_f<<<2048, 256, 0, stream>>>(row, deg_dis, E);
        k_dis<false><<<(N + 255) / 256, 256, 0, stream>>>(deg_dis, batch, cnt, pk, N);
        k_energy<<<2048, 256, 0, stream>>>(row, col, (const float4*)x, deg_dis, batch,
                                           g_energy, E);
    }
    k_final<<<1, 256, 0, stream>>>(logits, labels, g_energy, cnt, (float*)d_out);
}